// Round 9
// baseline (2235.275 us; speedup 1.0000x reference)
//
#include <hip/hip_runtime.h>

typedef unsigned short u16;
typedef unsigned int u32;
typedef short bf16x8 __attribute__((ext_vector_type(8)));
typedef float f32x4 __attribute__((ext_vector_type(4)));

__device__ __forceinline__ float us2f(u16 u) {
  union { unsigned int i; float f; } x; x.i = ((unsigned int)u) << 16; return x.f;
}
__device__ __forceinline__ u16 f2bf(float f) {
  union { float f; unsigned int i; } x; x.f = f;
  unsigned int i = x.i;
  return (u16)((i + 0x7FFFu + ((i >> 16) & 1u)) >> 16);
}
// Runtime input-dtype probe: `probe` -> ln1_g, first element exactly 1.0.
// bf16: u16[0]=0x3F80 ; fp32 little-endian: u16[0]=0x0000.
__device__ __forceinline__ int probe_f32(const void* p) {
  return ((const u16*)p)[0] == 0;
}
__device__ __forceinline__ float ldf(const void* p, size_t i, int f32) {
  return f32 ? ((const float*)p)[i] : us2f(((const u16*)p)[i]);
}
__device__ __forceinline__ float4 ldf4(const void* p, size_t i, int f32) {
  if (f32) return *(const float4*)((const float*)p + i);
  const ushort4 t = *(const ushort4*)((const u16*)p + i);
  return make_float4(us2f(t.x), us2f(t.y), us2f(t.z), us2f(t.w));
}

// ---- tconv: transpose+convert one 64x64 tile W[k][n] -> Wt[n][k] bf16 ----
// src W [K rows][N cols] @ element offset off (probe dtype). One block/tile.
__device__ __forceinline__ void tconv(u16 (*t)[72], const void* W, size_t off,
    int K, int N, u16* dst, int k0, int n0, int f32, int tid) {
  const int rr = tid >> 2, rc = (tid & 3) * 16;
  const size_t src = off + (size_t)(k0 + rr) * N + n0 + rc;
  u16 tmp[16];
  if (f32) {
    const float* p = (const float*)W + src;
#pragma unroll
    for (int q = 0; q < 4; q++) {
      const float4 f = *(const float4*)(p + q * 4);
      tmp[q * 4 + 0] = f2bf(f.x); tmp[q * 4 + 1] = f2bf(f.y);
      tmp[q * 4 + 2] = f2bf(f.z); tmp[q * 4 + 3] = f2bf(f.w);
    }
  } else {
    const u16* p = (const u16*)W + src;
    *(bf16x8*)&tmp[0] = *(const bf16x8*)p;
    *(bf16x8*)&tmp[8] = *(const bf16x8*)(p + 8);
  }
#pragma unroll
  for (int j = 0; j < 16; j++) t[rr][rc + j] = tmp[j];
  __syncthreads();
  const int wr = tid >> 2, wc = (tid & 3) * 16;
  u16 ot[16];
#pragma unroll
  for (int j = 0; j < 16; j++) ot[j] = t[wc + j][wr];
  u16* d = dst + (size_t)(n0 + wr) * K + k0 + wc;
  *(bf16x8*)d = *(bf16x8*)&ot[0];
  *(bf16x8*)(d + 8) = *(bf16x8*)&ot[8];
}

// Per-layer weight conversion: Wq|Wk|Wv -> wt[0..786431] ([1536][512]),
// Wo -> +786432 ([512][512]), W1 -> +1048576 ([1024][512]),
// W2 -> +1572864 ([512][1024]), biases bf16 -> +2097152 [bqkv|bo|b1|b2].
// Grid 513 blocks x 256.
__global__ __launch_bounds__(256) void wconv_layer(const void* __restrict__ probe,
    const void* __restrict__ Wq, const void* __restrict__ Wk,
    const void* __restrict__ Wv, const void* __restrict__ Wo,
    const void* __restrict__ W1, const void* __restrict__ W2,
    const void* __restrict__ bq, const void* __restrict__ bk,
    const void* __restrict__ bv, const void* __restrict__ bo,
    const void* __restrict__ b1, const void* __restrict__ b2,
    size_t wO, size_t w1O, size_t bO, size_t b1O, u16* __restrict__ wt) {
  const int f32 = probe_f32(probe);
  __shared__ u16 t[64][72];
  const int bid = blockIdx.x, tid = threadIdx.x;
  if (bid < 192) {
    const int src = bid / 64, tt = bid % 64;
    const void* W = src == 0 ? Wq : (src == 1 ? Wk : Wv);
    tconv(t, W, wO, 512, 512, wt + src * 262144, (tt & 7) * 64, (tt >> 3) * 64, f32, tid);
  } else if (bid < 256) {
    const int tt = bid - 192;
    tconv(t, Wo, wO, 512, 512, wt + 786432, (tt & 7) * 64, (tt >> 3) * 64, f32, tid);
  } else if (bid < 384) {
    const int tt = bid - 256;  // W1 [512][1024]
    tconv(t, W1, w1O, 512, 1024, wt + 1048576, (tt & 7) * 64, (tt >> 3) * 64, f32, tid);
  } else if (bid < 512) {
    const int tt = bid - 384;  // W2 [1024][512]
    tconv(t, W2, w1O, 1024, 512, wt + 1572864, (tt & 15) * 64, (tt >> 4) * 64, f32, tid);
  } else {
    for (int i = tid; i < 4608; i += 256) {
      float v;
      if (i < 1536) {
        const int s = i >> 9, c = i & 511;
        v = ldf(s == 0 ? bq : (s == 1 ? bk : bv), bO + c, f32);
      } else if (i < 2048) v = ldf(bo, bO + (i - 1536), f32);
      else if (i < 3072) v = ldf(b1, b1O + (i - 2048), f32);
      else v = ldf(b2, bO + (i - 3072), f32);
      wt[2097152 + i] = f2bf(v);
    }
  }
}

// Node-MLP weights: mnW1 [64][256] -> wt[0..] ([256][64]); mnW2 [256][512]
// -> wt+16384 ([512][256]); biases -> wt+147456 [mnb1(256)|mnb2(512)].
__global__ __launch_bounds__(256) void wconv_node(const void* __restrict__ probe,
    const void* __restrict__ mnW1, const void* __restrict__ mnW2,
    const void* __restrict__ mnb1, const void* __restrict__ mnb2,
    u16* __restrict__ wt) {
  const int f32 = probe_f32(probe);
  __shared__ u16 t[64][72];
  const int bid = blockIdx.x, tid = threadIdx.x;
  if (bid < 4) {
    tconv(t, mnW1, 0, 64, 256, wt, 0, bid * 64, f32, tid);
  } else if (bid < 36) {
    const int tt = bid - 4;
    tconv(t, mnW2, 0, 256, 512, wt + 16384, (tt & 3) * 64, (tt >> 2) * 64, f32, tid);
  } else {
    for (int i = tid; i < 768; i += 256) {
      const float v = (i < 256) ? ldf(mnb1, i, f32) : ldf(mnb2, i - 256, f32);
      wt[147456 + i] = f2bf(v);
    }
  }
}

// ---------------- MFMA GEMM vs pre-transposed bf16 weights ---------------
// C = act(A@W + bias) (+ res). Wt: [N][K] bf16 ws. bias: bf16 ws [N] (may
// be null). Pipelined LDS double-buffer, one barrier per k-step; A and B
// staging are identical pure bf16x8 vector loads (no conversion VALU).
// A: [M,*] row stride lda; a_mode 1 = bf16 ws, 2 = probe input dtype.
// res: [M,N] ws bf16. C: ws bf16/fp32 row stride N. act 0/1/2.
// Block 256 = 4 waves; tile 128(M)xBN; wave 32xBN via 2xNT mfma 16x16x32.
// LDS: <128,32>: 41 KB; <64,64>: 55.3 KB. Requires BK/(256/BN) == 16.
template <int BN, int BK>
__global__ __launch_bounds__(256) void gemm_bt(
    const void* __restrict__ probe, const void* __restrict__ A, int a_mode,
    int lda, const u16* __restrict__ Wt, const u16* __restrict__ bias,
    const u16* __restrict__ res, void* __restrict__ C, int c_bf16, int M,
    int N, int K, int act) {
  const int in_f32 = probe_f32(probe);
  const int a_f32 = (a_mode == 2) ? in_f32 : 0;
  constexpr int NT = BN / 16;
  constexpr int KH = BK / 32;
  constexpr int LDK = BK + 8;
  constexpr int TPR = 256 / BN;  // B-staging threads per row (BK/TPR == 16)
  __shared__ u16 As[2][128][LDK];
  __shared__ u16 Bt[2][BN][LDK];
  const int tid = threadIdx.x;
  const int n0 = blockIdx.x * BN, m0 = blockIdx.y * 128;
  const int wv = tid >> 6, lane = tid & 63;
  const int lk = lane & 15, quad = lane >> 4;
  const int wm = wv * 32;

  f32x4 acc[2][NT];
#pragma unroll
  for (int i = 0; i < 2; i++)
#pragma unroll
    for (int j = 0; j < NT; j++) acc[i][j] = (f32x4){0.f, 0.f, 0.f, 0.f};

  const int sar = tid >> 1, sac = (tid & 1) * (BK / 2);   // A staging
  const int br = tid / TPR, bc = (tid % TPR) * 16;        // B staging

  u16 abuf[BK / 2], bbuf[16];
  auto loadA = [&](int k0) {
    if (a_f32) {
      const float* ap = (const float*)A + (size_t)(m0 + sar) * lda + k0 + sac;
#pragma unroll
      for (int q = 0; q < BK / 8; q++) {
        const float4 f = *(const float4*)(ap + q * 4);
        abuf[q * 4 + 0] = f2bf(f.x); abuf[q * 4 + 1] = f2bf(f.y);
        abuf[q * 4 + 2] = f2bf(f.z); abuf[q * 4 + 3] = f2bf(f.w);
      }
    } else {
      const u16* ap = (const u16*)A + (size_t)(m0 + sar) * lda + k0 + sac;
#pragma unroll
      for (int q = 0; q < BK / 16; q++)
        *(bf16x8*)&abuf[q * 8] = *(const bf16x8*)(ap + q * 8);
    }
  };
  auto loadW = [&](int k0) {
    const u16* p = Wt + (size_t)(n0 + br) * K + k0 + bc;
    *(bf16x8*)&bbuf[0] = *(const bf16x8*)p;
    *(bf16x8*)&bbuf[8] = *(const bf16x8*)(p + 8);
  };
  auto store = [&](int bi) {
#pragma unroll
    for (int q = 0; q < BK / 16; q++)
      *(bf16x8*)&As[bi][sar][sac + q * 8] = *(bf16x8*)&abuf[q * 8];
    *(bf16x8*)&Bt[bi][br][bc] = *(bf16x8*)&bbuf[0];
    *(bf16x8*)&Bt[bi][br][bc + 8] = *(bf16x8*)&bbuf[8];
  };

  const int nk = K / BK;
  loadA(0); loadW(0); store(0);
  __syncthreads();
  for (int kt = 0; kt < nk; kt++) {
    const int cur = kt & 1;
    if (kt + 1 < nk) { loadA((kt + 1) * BK); loadW((kt + 1) * BK); }
    bf16x8 af[2][KH], bfv[NT][KH];
#pragma unroll
    for (int i = 0; i < 2; i++)
#pragma unroll
      for (int h = 0; h < KH; h++)
        af[i][h] = *(const bf16x8*)&As[cur][wm + i * 16 + lk][h * 32 + quad * 8];
#pragma unroll
    for (int j = 0; j < NT; j++)
#pragma unroll
      for (int h = 0; h < KH; h++)
        bfv[j][h] = *(const bf16x8*)&Bt[cur][j * 16 + lk][h * 32 + quad * 8];
#pragma unroll
    for (int i = 0; i < 2; i++)
#pragma unroll
      for (int j = 0; j < NT; j++)
#pragma unroll
        for (int h = 0; h < KH; h++)
          acc[i][j] = __builtin_amdgcn_mfma_f32_16x16x32_bf16(
              af[i][h], bfv[j][h], acc[i][j], 0, 0, 0);
    if (kt + 1 < nk) store(cur ^ 1);
    __syncthreads();
  }

#pragma unroll
  for (int j = 0; j < NT; j++) {
    const int col = n0 + j * 16 + lk;
    const float bb = bias ? us2f(bias[col]) : 0.f;
#pragma unroll
    for (int i = 0; i < 2; i++) {
#pragma unroll
      for (int r = 0; r < 4; r++) {
        const int row = m0 + wm + i * 16 + quad * 4 + r;
        float t = acc[i][j][r] + bb;
        if (act == 1) t = t > 0.f ? t : 0.f;
        else if (act == 2) t = t >= 0.f ? t : 0.1f * t;
        if (res) t += us2f(res[(size_t)row * N + col]);
        if (c_bf16) ((u16*)C)[(size_t)row * N + col] = f2bf(t);
        else ((float*)C)[(size_t)row * N + col] = t;
      }
    }
  }
}

__global__ __launch_bounds__(256) void deg_kernel(const void* __restrict__ probe,
    u16* __restrict__ x, const int* __restrict__ ind, const int* __restrict__ outd,
    const void* __restrict__ ein, const void* __restrict__ eout) {
  const int f32 = probe_f32(probe);
  const int r = blockIdx.x, tid = threadIdx.x;
  int a = ind[r]; a = a < 0 ? 0 : (a > 8 ? 8 : a);
  int b = outd[r]; b = b < 0 ? 0 : (b > 8 ? 8 : b);
  const size_t base = (size_t)r * 512;
  for (int c = tid; c < 512; c += 256) {
    const float v = us2f(x[base + c]) + ldf(ein, (size_t)a * 512 + c, f32) +
                    ldf(eout, (size_t)b * 512 + c, f32);
    x[base + c] = f2bf(v);
  }
}

// ---- bias_pack: fuse attn_bias [B,N,N,H] (+ mask [B,N,N]) into per-head
// bf16 planes biasm[b][h][q][k]. Masked -> -3e38. Wide-read/LDS-transpose/
// wide-write. One block per (b,q) row.
__global__ __launch_bounds__(256) void bias_pack(const void* __restrict__ probe,
    const void* __restrict__ bias, const int* __restrict__ mask,
    u16* __restrict__ biasm) {
  const int f32 = probe_f32(probe);
  __shared__ u16 pl[4][1032];  // pad 1032: plane stride 2064B -> bank +4
  const int bq = blockIdx.x, t = threadIdx.x;
  const size_t rk = (size_t)bq * 1024;
  const u16 NB = f2bf(-3.0e38f);
#pragma unroll
  for (int j = 0; j < 4; j++) {
    const int k = t + j * 256;
    const int mv = mask[rk + k];
    float h0, h1, h2, h3;
    if (f32) {
      const float4 f = *(const float4*)((const float*)bias + (rk + k) * 4);
      h0 = f.x; h1 = f.y; h2 = f.z; h3 = f.w;
    } else {
      const ushort4 u = *(const ushort4*)((const u16*)bias + (rk + k) * 4);
      h0 = us2f(u.x); h1 = us2f(u.y); h2 = us2f(u.z); h3 = us2f(u.w);
    }
    pl[0][k] = mv ? NB : f2bf(h0);
    pl[1][k] = mv ? NB : f2bf(h1);
    pl[2][k] = mv ? NB : f2bf(h2);
    pl[3][k] = mv ? NB : f2bf(h3);
  }
  __syncthreads();
  const int b = bq >> 10, q = bq & 1023;
  const int p = t & 3, seg = t >> 2;  // plane, 16-elem segment
  u16* dst = biasm + (((size_t)(b * 4 + p)) << 20) + (size_t)q * 1024 + seg * 16;
  *(bf16x8*)dst = *(const bf16x8*)&pl[p][seg * 16];
  *(bf16x8*)(dst + 8) = *(const bf16x8*)&pl[p][seg * 16 + 8];
}

// ---------------- MFMA flash attention (pipelined) -----------------------
// QKV: fused bf16 [B*N][1536] (q 0-511, k 512-1023, v 1024-1535). O writes
// the q-plane (own rows + own head-column slice only; Q register-resident
// before any O store). LDS double-buffered K/V, one barrier per tile.
// Bias loads hoisted before the QK^T MFMA cluster. Defer-max (T13): when
// the tile max doesn't exceed the running max by >8, skip the O-rescale —
// branch is wave-uniform via __all (P bounded by e^8, f32 accum tolerant).
// biasm (if non-null): fused bf16 bias+mask planes [b][h][q][k].
__global__ __launch_bounds__(256) void attn_mfma(const void* __restrict__ probe,
    const u16* __restrict__ QKV, const void* __restrict__ bias,
    const int* __restrict__ mask, u16* __restrict__ O,
    const u16* __restrict__ biasm) {
  const int f32 = probe_f32(probe);
  __shared__ u16 Kls[2][32][136];
  __shared__ u16 Vt[2][128][40];
  __shared__ u16 Pl[4][16][40];
  const int b = blockIdx.z, h = blockIdx.y, q0 = blockIdx.x * 64;
  const int tid = threadIdx.x;
  const int wv = tid >> 6, lane = tid & 63;
  const int lk = lane & 15, quad = lane >> 4;
  const float scale = 0.08838834764831845f;
  const float NEG = -3.0e38f;

  const size_t qg = (size_t)(b * 1024 + q0 + wv * 16);
  const int lq = q0 + wv * 16;
  const u16* bm = biasm ? biasm + (((size_t)(b * 4 + h)) << 20) : (const u16*)0;

  bf16x8 qf[4];
#pragma unroll
  for (int c = 0; c < 4; c++)
    qf[c] = *(const bf16x8*)(QKV + (qg + lk) * 1536 + h * 128 + c * 32 + quad * 8);

  f32x4 o[8];
#pragma unroll
  for (int c = 0; c < 8; c++) o[c] = (f32x4){0.f, 0.f, 0.f, 0.f};
  float m_st[4], l_st[4];
#pragma unroll
  for (int r = 0; r < 4; r++) { m_st[r] = NEG; l_st[r] = 0.f; }

  const int kp = tid & 15, dseg = tid >> 4;

  bf16x8 ka, kb2, va, vb2;
  auto loadKV = [&](int k0) {
    const size_t r0 = (size_t)(b * 1024 + k0 + 2 * kp) * 1536 + h * 128 + dseg * 8;
    ka  = *(const bf16x8*)(QKV + r0 + 512);
    kb2 = *(const bf16x8*)(QKV + r0 + 512 + 1536);
    va  = *(const bf16x8*)(QKV + r0 + 1024);
    vb2 = *(const bf16x8*)(QKV + r0 + 1024 + 1536);
  };
  auto storeKV = [&](int bi) {
    *(bf16x8*)&Kls[bi][2 * kp][dseg * 8] = ka;
    *(bf16x8*)&Kls[bi][2 * kp + 1][dseg * 8] = kb2;
#pragma unroll
    for (int i = 0; i < 8; i++) {
      const unsigned int pk =
          ((unsigned int)(u16)vb2[i] << 16) | (unsigned int)(u16)va[i];
      *(unsigned int*)&Vt[bi][dseg * 8 + i][2 * kp] = pk;
    }
  };

  loadKV(0); storeKV(0);
  __syncthreads();

  for (int kt = 0; kt < 32; kt++) {
    const int cur = kt & 1;
    const int k0 = kt * 32;
    if (kt < 31) loadKV((kt + 1) * 32);

    float bv[2][4];
    if (bm) {
#pragma unroll
      for (int kh = 0; kh < 2; kh++)
#pragma unroll
        for (int r = 0; r < 4; r++)
          bv[kh][r] =
              us2f(bm[(size_t)(lq + quad * 4 + r) * 1024 + (k0 + kh * 16 + lk)]);
    }

    f32x4 sa[2];
#pragma unroll
    for (int kh = 0; kh < 2; kh++) {
      sa[kh] = (f32x4){0.f, 0.f, 0.f, 0.f};
#pragma unroll
      for (int c = 0; c < 4; c++) {
        const bf16x8 kf = *(const bf16x8*)&Kls[cur][kh * 16 + lk][c * 32 + quad * 8];
        sa[kh] = __builtin_amdgcn_mfma_f32_16x16x32_bf16(qf[c], kf, sa[kh], 0, 0, 0);
      }
    }
    float sv[2][4];
    if (bm) {
#pragma unroll
      for (int kh = 0; kh < 2; kh++)
#pragma unroll
        for (int r = 0; r < 4; r++)
          sv[kh][r] = sa[kh][r] * scale + bv[kh][r];
    } else {
#pragma unroll
      for (int kh = 0; kh < 2; kh++)
#pragma unroll
        for (int r = 0; r < 4; r++) {
          const size_t bidx = (qg + quad * 4 + r) * 1024 + (size_t)(k0 + kh * 16 + lk);
          const float s = sa[kh][r] * scale + ldf(bias, bidx * 4 + h, f32);
          sv[kh][r] = mask[bidx] ? NEG : s;
        }
    }
#pragma unroll
    for (int r = 0; r < 4; r++) {
      float lm = fmaxf(sv[0][r], sv[1][r]);
      lm = fmaxf(lm, __shfl_xor(lm, 1));
      lm = fmaxf(lm, __shfl_xor(lm, 2));
      lm = fmaxf(lm, __shfl_xor(lm, 4));
      lm = fmaxf(lm, __shfl_xor(lm, 8));
      if (__all(lm - m_st[r] <= 8.f)) {
        // defer-max: keep old running max; P bounded by e^8.
        const float p0 = (sv[0][r] <= -1e37f) ? 0.f : __expf(sv[0][r] - m_st[r]);
        const float p1 = (sv[1][r] <= -1e37f) ? 0.f : __expf(sv[1][r] - m_st[r]);
        float ts = p0 + p1;
        ts += __shfl_xor(ts, 1);
        ts += __shfl_xor(ts, 2);
        ts += __shfl_xor(ts, 4);
        ts += __shfl_xor(ts, 8);
        l_st[r] += ts;
        Pl[wv][quad * 4 + r][lk] = f2bf(p0);
        Pl[wv][quad * 4 + r][16 + lk] = f2bf(p1);
      } else {
        const float mn = fmaxf(m_st[r], lm);
        const float al = __expf(m_st[r] - mn);
        const float p0 = (sv[0][r] <= -1e37f) ? 0.f : __expf(sv[0][r] - mn);
        const float p1 = (sv[1][r] <= -1e37f) ? 0.f : __expf(sv[1][r] - mn);
        float ts = p0 + p1;
        ts += __shfl_xor(ts, 1);
        ts += __shfl_xor(ts, 2);
        ts += __shfl_xor(ts, 4);
        ts += __shfl_xor(ts, 8);
        m_st[r] = mn;
        l_st[r] = l_st[r] * al + ts;
        Pl[wv][quad * 4 + r][lk] = f2bf(p0);
        Pl[wv][quad * 4 + r][16 + lk] = f2bf(p1);
#pragma unroll
        for (int c = 0; c < 8; c++) o[c][r] *= al;
      }
    }
    const bf16x8 pa = *(const bf16x8*)&Pl[wv][lk][quad * 8];
#pragma unroll
    for (int c = 0; c < 8; c++) {
      const bf16x8 vf = *(const bf16x8*)&Vt[cur][c * 16 + lk][quad * 8];
      o[c] = __builtin_amdgcn_mfma_f32_16x16x32_bf16(pa, vf, o[c], 0, 0, 0);
    }
    if (kt < 31) storeKV(cur ^ 1);
    __syncthreads();
  }
#pragma unroll
  for (int r = 0; r < 4; r++) {
    const float invl = 1.f / fmaxf(l_st[r], 1e-20f);
    u16* op = O + (qg + quad * 4 + r) * 1536 + h * 128;
#pragma unroll
    for (int c = 0; c < 8; c++) op[c * 16 + lk] = f2bf(o[c][r] * invl);
  }
}

// LayerNorm(512): wave-per-row, no barriers. in/out ws bf16. g/b input
// dtype @ element offset gOff. Grid = rows/4, block 256 = 4 waves.
__global__ __launch_bounds__(256) void ln_kernel(const void* __restrict__ probe,
    const u16* __restrict__ in, const void* __restrict__ g,
    const void* __restrict__ bta, size_t gOff, u16* __restrict__ out) {
  const int f32 = probe_f32(probe);
  const int lane = threadIdx.x & 63, w = threadIdx.x >> 6;
  const size_t r = (size_t)blockIdx.x * 4 + w;
  const size_t base = r * 512 + lane * 8;
  const bf16x8 v = *(const bf16x8*)(in + base);
  float xv[8];
  float s = 0.f, sq = 0.f;
#pragma unroll
  for (int i = 0; i < 8; i++) {
    xv[i] = us2f((u16)v[i]);
    s += xv[i]; sq += xv[i] * xv[i];
  }
#pragma unroll
  for (int off = 32; off > 0; off >>= 1) {
    s += __shfl_xor(s, off);
    sq += __shfl_xor(sq, off);
  }
  const float m = s * (1.f / 512.f);
  const float var = fmaxf(sq * (1.f / 512.f) - m * m, 0.f);
  const float rs = rsqrtf(var + 1e-5f);
  const float4 g0 = ldf4(g, gOff + lane * 8, f32);
  const float4 g1 = ldf4(g, gOff + lane * 8 + 4, f32);
  const float4 b0 = ldf4(bta, gOff + lane * 8, f32);
  const float4 b1 = ldf4(bta, gOff + lane * 8 + 4, f32);
  const float gg[8] = {g0.x, g0.y, g0.z, g0.w, g1.x, g1.y, g1.z, g1.w};
  const float bb[8] = {b0.x, b0.y, b0.z, b0.w, b1.x, b1.y, b1.z, b1.w};
  bf16x8 ov;
#pragma unroll
  for (int i = 0; i < 8; i++) ov[i] = (short)f2bf((xv[i] - m) * rs * gg[i] + bb[i]);
  *(bf16x8*)(out + base) = ov;
}

__global__ __launch_bounds__(256) void final_kernel(const void* __restrict__ probe,
    const u16* __restrict__ x, const int* __restrict__ po,
    const void* __restrict__ W1, const void* __restrict__ b1,
    const void* __restrict__ W2, const void* __restrict__ b2,
    void* __restrict__ out) {
  const int f32 = probe_f32(probe);
  __shared__ float rsr[512];
  __shared__ float red[256];
  const int r = blockIdx.x, tid = threadIdx.x;
  const int b = r >> 7, p = r & 127;
  int n = po[b * 128 + p]; n = n < 0 ? 0 : (n > 1023 ? 1023 : n);
  const u16* row = x + ((size_t)(b * 1024 + n)) * 512;
  rsr[tid] = us2f(row[tid]); rsr[tid + 256] = us2f(row[tid + 256]);
  __syncthreads();
  float t = ldf(b1, tid, f32);
  for (int k = 0; k < 512; k++) t += rsr[k] * ldf(W1, (size_t)k * 256 + tid, f32);
  t = t >= 0.f ? t : 0.1f * t;
  red[tid] = t * ldf(W2, tid, f32);
  __syncthreads();
  for (int off = 128; off > 0; off >>= 1) {
    if (tid < off) red[tid] += red[tid + off];
    __syncthreads();
  }
  if (tid == 0) {
    const float v = red[0] + ldf(b2, 0, f32);
    if (f32) ((float*)out)[r] = v; else ((u16*)out)[r] = f2bf(v);
  }
}

extern "C" void kernel_launch(void* const* d_in, const int* in_sizes, int n_in,
                              void* d_out, int out_size, void* d_ws, size_t ws_size,
                              hipStream_t stream) {
  (void)in_sizes; (void)out_size;
  const int D = 512, HID = 1024, L = 6;
  const int M = 8192;

  const int sh = (n_in >= 33) ? 0 : 1;
#define IN(k) d_in[(k) - (((k) >= 4) ? sh : 0)]
  const void* nf   = IN(0);
  const int* ind   = (const int*)IN(1);
  const int* outd  = (const int*)IN(2);
  const int* amask = (const int*)IN(4);
  const int* po    = (const int*)IN(5);
  const void* abias = IN(6);
  const void* ein  = IN(7);
  const void* eout = IN(8);
  const void* mnW1 = IN(9);  const void* mnb1 = IN(10);
  const void* mnW2 = IN(11); const void* mnb2 = IN(12);
  const void* Wq = IN(13); const void* bq = IN(14);
  const void* Wk = IN(15); const void* bk = IN(16);
  const void* Wv = IN(17); const void* bv = IN(18);
  const void* Wo = IN(19); const void* bo = IN(20);
  const void* ln1g = IN(21); const void* ln1b = IN(22);
  const void* W1 = IN(23); const void* b1 = IN(24);
  const void* W2 = IN(25); const void* b2 = IN(26);
  const void* ln2g = IN(27); const void* ln2b = IN(28);
  const void* oW1 = IN(29); const void* ob1 = IN(30);
  const void* oW2 = IN(31); const void* ob2 = IN(32);
#undef IN
  const void* probe = ln1g;

  // ws layout: x bf16 @0 (8M) | yb bf16 @8M (8M) | qkv bf16 [M][1536]
  // @16M (24M) | wt bf16 @40M (~4.2M: per-layer transposed weights+biases)
  // | biasm bf16 @45M (64M, if ws_size >= 109M; known >=112M from R1).
  // h1b = yb; hidb aliases qkv region (16M <= 24M).
  char* wsb = (char*)d_ws;
  u16* x   = (u16*)wsb;
  u16* yb  = (u16*)(wsb + ((size_t)8 << 20));
  u16* qkv = (u16*)(wsb + ((size_t)16 << 20));
  u16* wt  = (u16*)(wsb + ((size_t)40 << 20));
  u16* h1b = yb;
  u16* hidb = qkv;
  u16* biasm = (ws_size >= ((size_t)109 << 20))
                   ? (u16*)(wsb + ((size_t)45 << 20)) : (u16*)0;

  dim3 blk(256);
  if (biasm) bias_pack<<<8192, blk, 0, stream>>>(probe, abias, amask, biasm);
  // node MLP: convert weights once, then MFMA GEMMs (overwritten at layer 0)
  wconv_node<<<37, blk, 0, stream>>>(probe, mnW1, mnW2, mnb1, mnb2, wt);
  gemm_bt<64, 64><<<dim3(4, M / 128), blk, 0, stream>>>(probe, nf, 2, 64, wt, wt + 147456, nullptr, h1b, 1, M, 256, 64, 2);
  gemm_bt<64, 64><<<dim3(8, M / 128), blk, 0, stream>>>(probe, h1b, 1, 256, wt + 16384, wt + 147456 + 256, nullptr, x, 1, M, D, 256, 0);
  deg_kernel<<<M, blk, 0, stream>>>(probe, x, ind, outd, ein, eout);

  for (int l = 0; l < L; l++) {
    const size_t wO = (size_t)l * D * D, bO = (size_t)l * D;
    const size_t w1O = (size_t)l * D * HID, b1O = (size_t)l * HID;
    wconv_layer<<<513, blk, 0, stream>>>(probe, Wq, Wk, Wv, Wo, W1, W2,
                                         bq, bk, bv, bo, b1, b2, wO, w1O, bO, b1O, wt);
    gemm_bt<128, 32><<<dim3(12, M / 128), blk, 0, stream>>>(probe, x, 1, 512, wt, wt + 2097152, nullptr, qkv, 1, M, 1536, 512, 0);
    attn_mfma<<<dim3(16, 4, 8), blk, 0, stream>>>(probe, qkv, abias, amask, qkv, biasm);
    gemm_bt<64, 64><<<dim3(8, M / 128), blk, 0, stream>>>(probe, qkv, 1, 1536, wt + 786432, wt + 2097152 + 1536, x, yb, 1, M, D, D, 0);
    ln_kernel<<<M / 4, blk, 0, stream>>>(probe, yb, ln1g, ln1b, bO, x);
    gemm_bt<128, 32><<<dim3(8, M / 128), blk, 0, stream>>>(probe, x, 1, 512, wt + 1048576, wt + 2097152 + 2048, nullptr, hidb, 1, M, HID, 512, 1);
    gemm_bt<64, 64><<<dim3(8, M / 128), blk, 0, stream>>>(probe, hidb, 1, 1024, wt + 1572864, wt + 2097152 + 3072, x, yb, 1, M, D, HID, 0);
    ln_kernel<<<M / 4, blk, 0, stream>>>(probe, yb, ln2g, ln2b, bO, x);
  }
  final_kernel<<<1024, blk, 0, stream>>>(probe, x, po, oW1, ob1, oW2, ob2, d_out);
}

// Round 10
// 1624.671 us; speedup vs baseline: 1.3758x; 1.3758x over previous
//
#include <hip/hip_runtime.h>

typedef unsigned short u16;
typedef unsigned int u32;
typedef short bf16x8 __attribute__((ext_vector_type(8)));
typedef float f32x4 __attribute__((ext_vector_type(4)));

__device__ __forceinline__ float us2f(u16 u) {
  union { unsigned int i; float f; } x; x.i = ((unsigned int)u) << 16; return x.f;
}
__device__ __forceinline__ u16 f2bf(float f) {
  union { float f; unsigned int i; } x; x.f = f;
  unsigned int i = x.i;
  return (u16)((i + 0x7FFFu + ((i >> 16) & 1u)) >> 16);
}
// Runtime input-dtype probe: `probe` -> ln1_g, first element exactly 1.0.
// bf16: u16[0]=0x3F80 ; fp32 little-endian: u16[0]=0x0000.
__device__ __forceinline__ int probe_f32(const void* p) {
  return ((const u16*)p)[0] == 0;
}
__device__ __forceinline__ float ldf(const void* p, size_t i, int f32) {
  return f32 ? ((const float*)p)[i] : us2f(((const u16*)p)[i]);
}
__device__ __forceinline__ float4 ldf4(const void* p, size_t i, int f32) {
  if (f32) return *(const float4*)((const float*)p + i);
  const ushort4 t = *(const ushort4*)((const u16*)p + i);
  return make_float4(us2f(t.x), us2f(t.y), us2f(t.z), us2f(t.w));
}

// ---- tconv: transpose+convert one 64x64 tile W[k][n] -> Wt[n][k] bf16 ----
// src W [K rows][N cols] @ element offset off (probe dtype). One block/tile.
__device__ __forceinline__ void tconv(u16 (*t)[72], const void* W, size_t off,
    int K, int N, u16* dst, int k0, int n0, int f32, int tid) {
  const int rr = tid >> 2, rc = (tid & 3) * 16;
  const size_t src = off + (size_t)(k0 + rr) * N + n0 + rc;
  u16 tmp[16];
  if (f32) {
    const float* p = (const float*)W + src;
#pragma unroll
    for (int q = 0; q < 4; q++) {
      const float4 f = *(const float4*)(p + q * 4);
      tmp[q * 4 + 0] = f2bf(f.x); tmp[q * 4 + 1] = f2bf(f.y);
      tmp[q * 4 + 2] = f2bf(f.z); tmp[q * 4 + 3] = f2bf(f.w);
    }
  } else {
    const u16* p = (const u16*)W + src;
    *(bf16x8*)&tmp[0] = *(const bf16x8*)p;
    *(bf16x8*)&tmp[8] = *(const bf16x8*)(p + 8);
  }
#pragma unroll
  for (int j = 0; j < 16; j++) t[rr][rc + j] = tmp[j];
  __syncthreads();
  const int wr = tid >> 2, wc = (tid & 3) * 16;
  u16 ot[16];
#pragma unroll
  for (int j = 0; j < 16; j++) ot[j] = t[wc + j][wr];
  u16* d = dst + (size_t)(n0 + wr) * K + k0 + wc;
  *(bf16x8*)d = *(bf16x8*)&ot[0];
  *(bf16x8*)(d + 8) = *(bf16x8*)&ot[8];
}

// Per-layer weight conversion: Wq|Wk|Wv -> wt[0..786431] ([1536][512]),
// Wo -> +786432 ([512][512]), W1 -> +1048576 ([1024][512]),
// W2 -> +1572864 ([512][1024]), biases bf16 -> +2097152 [bqkv|bo|b1|b2].
// Grid 513 blocks x 256.
__global__ __launch_bounds__(256) void wconv_layer(const void* __restrict__ probe,
    const void* __restrict__ Wq, const void* __restrict__ Wk,
    const void* __restrict__ Wv, const void* __restrict__ Wo,
    const void* __restrict__ W1, const void* __restrict__ W2,
    const void* __restrict__ bq, const void* __restrict__ bk,
    const void* __restrict__ bv, const void* __restrict__ bo,
    const void* __restrict__ b1, const void* __restrict__ b2,
    size_t wO, size_t w1O, size_t bO, size_t b1O, u16* __restrict__ wt) {
  const int f32 = probe_f32(probe);
  __shared__ u16 t[64][72];
  const int bid = blockIdx.x, tid = threadIdx.x;
  if (bid < 192) {
    const int src = bid / 64, tt = bid % 64;
    const void* W = src == 0 ? Wq : (src == 1 ? Wk : Wv);
    tconv(t, W, wO, 512, 512, wt + src * 262144, (tt & 7) * 64, (tt >> 3) * 64, f32, tid);
  } else if (bid < 256) {
    const int tt = bid - 192;
    tconv(t, Wo, wO, 512, 512, wt + 786432, (tt & 7) * 64, (tt >> 3) * 64, f32, tid);
  } else if (bid < 384) {
    const int tt = bid - 256;  // W1 [512][1024]
    tconv(t, W1, w1O, 512, 1024, wt + 1048576, (tt & 7) * 64, (tt >> 3) * 64, f32, tid);
  } else if (bid < 512) {
    const int tt = bid - 384;  // W2 [1024][512]
    tconv(t, W2, w1O, 1024, 512, wt + 1572864, (tt & 15) * 64, (tt >> 4) * 64, f32, tid);
  } else {
    for (int i = tid; i < 4608; i += 256) {
      float v;
      if (i < 1536) {
        const int s = i >> 9, c = i & 511;
        v = ldf(s == 0 ? bq : (s == 1 ? bk : bv), bO + c, f32);
      } else if (i < 2048) v = ldf(bo, bO + (i - 1536), f32);
      else if (i < 3072) v = ldf(b1, b1O + (i - 2048), f32);
      else v = ldf(b2, bO + (i - 3072), f32);
      wt[2097152 + i] = f2bf(v);
    }
  }
}

// Node-MLP weights: mnW1 [64][256] -> wt[0..] ([256][64]); mnW2 [256][512]
// -> wt+16384 ([512][256]); biases -> wt+147456 [mnb1(256)|mnb2(512)].
__global__ __launch_bounds__(256) void wconv_node(const void* __restrict__ probe,
    const void* __restrict__ mnW1, const void* __restrict__ mnW2,
    const void* __restrict__ mnb1, const void* __restrict__ mnb2,
    u16* __restrict__ wt) {
  const int f32 = probe_f32(probe);
  __shared__ u16 t[64][72];
  const int bid = blockIdx.x, tid = threadIdx.x;
  if (bid < 4) {
    tconv(t, mnW1, 0, 64, 256, wt, 0, bid * 64, f32, tid);
  } else if (bid < 36) {
    const int tt = bid - 4;
    tconv(t, mnW2, 0, 256, 512, wt + 16384, (tt & 3) * 64, (tt >> 2) * 64, f32, tid);
  } else {
    for (int i = tid; i < 768; i += 256) {
      const float v = (i < 256) ? ldf(mnb1, i, f32) : ldf(mnb2, i - 256, f32);
      wt[147456 + i] = f2bf(v);
    }
  }
}

// ---------------- MFMA GEMM vs pre-transposed bf16 weights ---------------
// C = act(A@W + bias) (+ res). Wt: [N][K] bf16 ws. bias: bf16 ws [N] (may
// be null). Pipelined LDS double-buffer, one barrier per k-step; A and B
// staging are identical pure bf16x8 vector loads (no conversion VALU).
// A: [M,*] row stride lda; a_mode 1 = bf16 ws, 2 = probe input dtype.
// res: [M,N] ws bf16. C: ws bf16/fp32 row stride N. act 0/1/2.
// Block 256 = 4 waves; tile 128(M)xBN; wave 32xBN via 2xNT mfma 16x16x32.
// LDS: <128,32>: 41 KB; <64,64>: 55.3 KB. Requires BK/(256/BN) == 16.
template <int BN, int BK>
__global__ __launch_bounds__(256) void gemm_bt(
    const void* __restrict__ probe, const void* __restrict__ A, int a_mode,
    int lda, const u16* __restrict__ Wt, const u16* __restrict__ bias,
    const u16* __restrict__ res, void* __restrict__ C, int c_bf16, int M,
    int N, int K, int act) {
  const int in_f32 = probe_f32(probe);
  const int a_f32 = (a_mode == 2) ? in_f32 : 0;
  constexpr int NT = BN / 16;
  constexpr int KH = BK / 32;
  constexpr int LDK = BK + 8;
  constexpr int TPR = 256 / BN;  // B-staging threads per row (BK/TPR == 16)
  __shared__ u16 As[2][128][LDK];
  __shared__ u16 Bt[2][BN][LDK];
  const int tid = threadIdx.x;
  const int n0 = blockIdx.x * BN, m0 = blockIdx.y * 128;
  const int wv = tid >> 6, lane = tid & 63;
  const int lk = lane & 15, quad = lane >> 4;
  const int wm = wv * 32;

  f32x4 acc[2][NT];
#pragma unroll
  for (int i = 0; i < 2; i++)
#pragma unroll
    for (int j = 0; j < NT; j++) acc[i][j] = (f32x4){0.f, 0.f, 0.f, 0.f};

  const int sar = tid >> 1, sac = (tid & 1) * (BK / 2);   // A staging
  const int br = tid / TPR, bc = (tid % TPR) * 16;        // B staging

  u16 abuf[BK / 2], bbuf[16];
  auto loadA = [&](int k0) {
    if (a_f32) {
      const float* ap = (const float*)A + (size_t)(m0 + sar) * lda + k0 + sac;
#pragma unroll
      for (int q = 0; q < BK / 8; q++) {
        const float4 f = *(const float4*)(ap + q * 4);
        abuf[q * 4 + 0] = f2bf(f.x); abuf[q * 4 + 1] = f2bf(f.y);
        abuf[q * 4 + 2] = f2bf(f.z); abuf[q * 4 + 3] = f2bf(f.w);
      }
    } else {
      const u16* ap = (const u16*)A + (size_t)(m0 + sar) * lda + k0 + sac;
#pragma unroll
      for (int q = 0; q < BK / 16; q++)
        *(bf16x8*)&abuf[q * 8] = *(const bf16x8*)(ap + q * 8);
    }
  };
  auto loadW = [&](int k0) {
    const u16* p = Wt + (size_t)(n0 + br) * K + k0 + bc;
    *(bf16x8*)&bbuf[0] = *(const bf16x8*)p;
    *(bf16x8*)&bbuf[8] = *(const bf16x8*)(p + 8);
  };
  auto store = [&](int bi) {
#pragma unroll
    for (int q = 0; q < BK / 16; q++)
      *(bf16x8*)&As[bi][sar][sac + q * 8] = *(bf16x8*)&abuf[q * 8];
    *(bf16x8*)&Bt[bi][br][bc] = *(bf16x8*)&bbuf[0];
    *(bf16x8*)&Bt[bi][br][bc + 8] = *(bf16x8*)&bbuf[8];
  };

  const int nk = K / BK;
  loadA(0); loadW(0); store(0);
  __syncthreads();
  for (int kt = 0; kt < nk; kt++) {
    const int cur = kt & 1;
    if (kt + 1 < nk) { loadA((kt + 1) * BK); loadW((kt + 1) * BK); }
    bf16x8 af[2][KH], bfv[NT][KH];
#pragma unroll
    for (int i = 0; i < 2; i++)
#pragma unroll
      for (int h = 0; h < KH; h++)
        af[i][h] = *(const bf16x8*)&As[cur][wm + i * 16 + lk][h * 32 + quad * 8];
#pragma unroll
    for (int j = 0; j < NT; j++)
#pragma unroll
      for (int h = 0; h < KH; h++)
        bfv[j][h] = *(const bf16x8*)&Bt[cur][j * 16 + lk][h * 32 + quad * 8];
#pragma unroll
    for (int i = 0; i < 2; i++)
#pragma unroll
      for (int j = 0; j < NT; j++)
#pragma unroll
        for (int h = 0; h < KH; h++)
          acc[i][j] = __builtin_amdgcn_mfma_f32_16x16x32_bf16(
              af[i][h], bfv[j][h], acc[i][j], 0, 0, 0);
    if (kt + 1 < nk) store(cur ^ 1);
    __syncthreads();
  }

#pragma unroll
  for (int j = 0; j < NT; j++) {
    const int col = n0 + j * 16 + lk;
    const float bb = bias ? us2f(bias[col]) : 0.f;
#pragma unroll
    for (int i = 0; i < 2; i++) {
#pragma unroll
      for (int r = 0; r < 4; r++) {
        const int row = m0 + wm + i * 16 + quad * 4 + r;
        float t = acc[i][j][r] + bb;
        if (act == 1) t = t > 0.f ? t : 0.f;
        else if (act == 2) t = t >= 0.f ? t : 0.1f * t;
        if (res) t += us2f(res[(size_t)row * N + col]);
        if (c_bf16) ((u16*)C)[(size_t)row * N + col] = f2bf(t);
        else ((float*)C)[(size_t)row * N + col] = t;
      }
    }
  }
}

__global__ __launch_bounds__(256) void deg_kernel(const void* __restrict__ probe,
    u16* __restrict__ x, const int* __restrict__ ind, const int* __restrict__ outd,
    const void* __restrict__ ein, const void* __restrict__ eout) {
  const int f32 = probe_f32(probe);
  const int r = blockIdx.x, tid = threadIdx.x;
  int a = ind[r]; a = a < 0 ? 0 : (a > 8 ? 8 : a);
  int b = outd[r]; b = b < 0 ? 0 : (b > 8 ? 8 : b);
  const size_t base = (size_t)r * 512;
  for (int c = tid; c < 512; c += 256) {
    const float v = us2f(x[base + c]) + ldf(ein, (size_t)a * 512 + c, f32) +
                    ldf(eout, (size_t)b * 512 + c, f32);
    x[base + c] = f2bf(v);
  }
}

// ---- bias_pack: fuse attn_bias [B,N,N,H] (+ mask [B,N,N]) into per-head
// bf16 planes biasm[b][h][q][k]. Masked -> -3e38. Wide-read/LDS-transpose/
// wide-write. One block per (b,q) row.
__global__ __launch_bounds__(256) void bias_pack(const void* __restrict__ probe,
    const void* __restrict__ bias, const int* __restrict__ mask,
    u16* __restrict__ biasm) {
  const int f32 = probe_f32(probe);
  __shared__ u16 pl[4][1032];  // pad 1032: plane stride 2064B -> bank +4
  const int bq = blockIdx.x, t = threadIdx.x;
  const size_t rk = (size_t)bq * 1024;
  const u16 NB = f2bf(-3.0e38f);
#pragma unroll
  for (int j = 0; j < 4; j++) {
    const int k = t + j * 256;
    const int mv = mask[rk + k];
    float h0, h1, h2, h3;
    if (f32) {
      const float4 f = *(const float4*)((const float*)bias + (rk + k) * 4);
      h0 = f.x; h1 = f.y; h2 = f.z; h3 = f.w;
    } else {
      const ushort4 u = *(const ushort4*)((const u16*)bias + (rk + k) * 4);
      h0 = us2f(u.x); h1 = us2f(u.y); h2 = us2f(u.z); h3 = us2f(u.w);
    }
    pl[0][k] = mv ? NB : f2bf(h0);
    pl[1][k] = mv ? NB : f2bf(h1);
    pl[2][k] = mv ? NB : f2bf(h2);
    pl[3][k] = mv ? NB : f2bf(h3);
  }
  __syncthreads();
  const int b = bq >> 10, q = bq & 1023;
  const int p = t & 3, seg = t >> 2;  // plane, 16-elem segment
  u16* dst = biasm + (((size_t)(b * 4 + p)) << 20) + (size_t)q * 1024 + seg * 16;
  *(bf16x8*)dst = *(const bf16x8*)&pl[p][seg * 16];
  *(bf16x8*)(dst + 8) = *(const bf16x8*)&pl[p][seg * 16 + 8];
}

// ---------------- MFMA flash attention (pipelined) -----------------------
// QKV: fused bf16 [B*N][1536] (q 0-511, k 512-1023, v 1024-1535). O writes
// the q-plane (own rows + own head-column slice only; Q register-resident
// before any O store). LDS double-buffered K/V, one barrier per tile.
// Bias loads hoisted before the QK^T MFMA cluster (latency hides under it).
// Softmax: round-7 unconditional-rescale form — the defer-max branch pair
// (round 9) doubled live state, VGPR 88->192, occupancy 20->11.5%, 2.6x
// slower. Keep single-path.
// biasm (if non-null): fused bf16 bias+mask planes [b][h][q][k].
__global__ __launch_bounds__(256) void attn_mfma(const void* __restrict__ probe,
    const u16* __restrict__ QKV, const void* __restrict__ bias,
    const int* __restrict__ mask, u16* __restrict__ O,
    const u16* __restrict__ biasm) {
  const int f32 = probe_f32(probe);
  __shared__ u16 Kls[2][32][136];
  __shared__ u16 Vt[2][128][40];
  __shared__ u16 Pl[4][16][40];
  const int b = blockIdx.z, h = blockIdx.y, q0 = blockIdx.x * 64;
  const int tid = threadIdx.x;
  const int wv = tid >> 6, lane = tid & 63;
  const int lk = lane & 15, quad = lane >> 4;
  const float scale = 0.08838834764831845f;
  const float NEG = -3.0e38f;

  const size_t qg = (size_t)(b * 1024 + q0 + wv * 16);
  const int lq = q0 + wv * 16;
  const u16* bm = biasm ? biasm + (((size_t)(b * 4 + h)) << 20) : (const u16*)0;

  bf16x8 qf[4];
#pragma unroll
  for (int c = 0; c < 4; c++)
    qf[c] = *(const bf16x8*)(QKV + (qg + lk) * 1536 + h * 128 + c * 32 + quad * 8);

  f32x4 o[8];
#pragma unroll
  for (int c = 0; c < 8; c++) o[c] = (f32x4){0.f, 0.f, 0.f, 0.f};
  float m_st[4], l_st[4];
#pragma unroll
  for (int r = 0; r < 4; r++) { m_st[r] = NEG; l_st[r] = 0.f; }

  const int kp = tid & 15, dseg = tid >> 4;

  bf16x8 ka, kb2, va, vb2;
  auto loadKV = [&](int k0) {
    const size_t r0 = (size_t)(b * 1024 + k0 + 2 * kp) * 1536 + h * 128 + dseg * 8;
    ka  = *(const bf16x8*)(QKV + r0 + 512);
    kb2 = *(const bf16x8*)(QKV + r0 + 512 + 1536);
    va  = *(const bf16x8*)(QKV + r0 + 1024);
    vb2 = *(const bf16x8*)(QKV + r0 + 1024 + 1536);
  };
  auto storeKV = [&](int bi) {
    *(bf16x8*)&Kls[bi][2 * kp][dseg * 8] = ka;
    *(bf16x8*)&Kls[bi][2 * kp + 1][dseg * 8] = kb2;
#pragma unroll
    for (int i = 0; i < 8; i++) {
      const unsigned int pk =
          ((unsigned int)(u16)vb2[i] << 16) | (unsigned int)(u16)va[i];
      *(unsigned int*)&Vt[bi][dseg * 8 + i][2 * kp] = pk;
    }
  };

  loadKV(0); storeKV(0);
  __syncthreads();

  for (int kt = 0; kt < 32; kt++) {
    const int cur = kt & 1;
    const int k0 = kt * 32;
    if (kt < 31) loadKV((kt + 1) * 32);

    // bias loads issued BEFORE the MFMA cluster -> latency hidden under it
    float bv[2][4];
    if (bm) {
#pragma unroll
      for (int kh = 0; kh < 2; kh++)
#pragma unroll
        for (int r = 0; r < 4; r++)
          bv[kh][r] =
              us2f(bm[(size_t)(lq + quad * 4 + r) * 1024 + (k0 + kh * 16 + lk)]);
    }

    f32x4 sa[2];
#pragma unroll
    for (int kh = 0; kh < 2; kh++) {
      sa[kh] = (f32x4){0.f, 0.f, 0.f, 0.f};
#pragma unroll
      for (int c = 0; c < 4; c++) {
        const bf16x8 kf = *(const bf16x8*)&Kls[cur][kh * 16 + lk][c * 32 + quad * 8];
        sa[kh] = __builtin_amdgcn_mfma_f32_16x16x32_bf16(qf[c], kf, sa[kh], 0, 0, 0);
      }
    }
    float sv[2][4];
    if (bm) {
#pragma unroll
      for (int kh = 0; kh < 2; kh++)
#pragma unroll
        for (int r = 0; r < 4; r++)
          sv[kh][r] = sa[kh][r] * scale + bv[kh][r];
    } else {
#pragma unroll
      for (int kh = 0; kh < 2; kh++)
#pragma unroll
        for (int r = 0; r < 4; r++) {
          const size_t bidx = (qg + quad * 4 + r) * 1024 + (size_t)(k0 + kh * 16 + lk);
          const float s = sa[kh][r] * scale + ldf(bias, bidx * 4 + h, f32);
          sv[kh][r] = mask[bidx] ? NEG : s;
        }
    }
#pragma unroll
    for (int r = 0; r < 4; r++) {
      float lm = fmaxf(sv[0][r], sv[1][r]);
      lm = fmaxf(lm, __shfl_xor(lm, 1));
      lm = fmaxf(lm, __shfl_xor(lm, 2));
      lm = fmaxf(lm, __shfl_xor(lm, 4));
      lm = fmaxf(lm, __shfl_xor(lm, 8));
      const float mn = fmaxf(m_st[r], lm);
      const float al = __expf(m_st[r] - mn);
      const float p0 = (sv[0][r] <= -1e37f) ? 0.f : __expf(sv[0][r] - mn);
      const float p1 = (sv[1][r] <= -1e37f) ? 0.f : __expf(sv[1][r] - mn);
      float ts = p0 + p1;
      ts += __shfl_xor(ts, 1);
      ts += __shfl_xor(ts, 2);
      ts += __shfl_xor(ts, 4);
      ts += __shfl_xor(ts, 8);
      m_st[r] = mn;
      l_st[r] = l_st[r] * al + ts;
      Pl[wv][quad * 4 + r][lk] = f2bf(p0);
      Pl[wv][quad * 4 + r][16 + lk] = f2bf(p1);
#pragma unroll
      for (int c = 0; c < 8; c++) o[c][r] *= al;
    }
    const bf16x8 pa = *(const bf16x8*)&Pl[wv][lk][quad * 8];
#pragma unroll
    for (int c = 0; c < 8; c++) {
      const bf16x8 vf = *(const bf16x8*)&Vt[cur][c * 16 + lk][quad * 8];
      o[c] = __builtin_amdgcn_mfma_f32_16x16x32_bf16(pa, vf, o[c], 0, 0, 0);
    }
    if (kt < 31) storeKV(cur ^ 1);
    __syncthreads();
  }
#pragma unroll
  for (int r = 0; r < 4; r++) {
    const float invl = 1.f / fmaxf(l_st[r], 1e-20f);
    u16* op = O + (qg + quad * 4 + r) * 1536 + h * 128;
#pragma unroll
    for (int c = 0; c < 8; c++) op[c * 16 + lk] = f2bf(o[c][r] * invl);
  }
}

// LayerNorm(512): wave-per-row, no barriers. in/out ws bf16. g/b input
// dtype @ element offset gOff. Grid = rows/4, block 256 = 4 waves.
__global__ __launch_bounds__(256) void ln_kernel(const void* __restrict__ probe,
    const u16* __restrict__ in, const void* __restrict__ g,
    const void* __restrict__ bta, size_t gOff, u16* __restrict__ out) {
  const int f32 = probe_f32(probe);
  const int lane = threadIdx.x & 63, w = threadIdx.x >> 6;
  const size_t r = (size_t)blockIdx.x * 4 + w;
  const size_t base = r * 512 + lane * 8;
  const bf16x8 v = *(const bf16x8*)(in + base);
  float xv[8];
  float s = 0.f, sq = 0.f;
#pragma unroll
  for (int i = 0; i < 8; i++) {
    xv[i] = us2f((u16)v[i]);
    s += xv[i]; sq += xv[i] * xv[i];
  }
#pragma unroll
  for (int off = 32; off > 0; off >>= 1) {
    s += __shfl_xor(s, off);
    sq += __shfl_xor(sq, off);
  }
  const float m = s * (1.f / 512.f);
  const float var = fmaxf(sq * (1.f / 512.f) - m * m, 0.f);
  const float rs = rsqrtf(var + 1e-5f);
  const float4 g0 = ldf4(g, gOff + lane * 8, f32);
  const float4 g1 = ldf4(g, gOff + lane * 8 + 4, f32);
  const float4 b0 = ldf4(bta, gOff + lane * 8, f32);
  const float4 b1 = ldf4(bta, gOff + lane * 8 + 4, f32);
  const float gg[8] = {g0.x, g0.y, g0.z, g0.w, g1.x, g1.y, g1.z, g1.w};
  const float bb[8] = {b0.x, b0.y, b0.z, b0.w, b1.x, b1.y, b1.z, b1.w};
  bf16x8 ov;
#pragma unroll
  for (int i = 0; i < 8; i++) ov[i] = (short)f2bf((xv[i] - m) * rs * gg[i] + bb[i]);
  *(bf16x8*)(out + base) = ov;
}

__global__ __launch_bounds__(256) void final_kernel(const void* __restrict__ probe,
    const u16* __restrict__ x, const int* __restrict__ po,
    const void* __restrict__ W1, const void* __restrict__ b1,
    const void* __restrict__ W2, const void* __restrict__ b2,
    void* __restrict__ out) {
  const int f32 = probe_f32(probe);
  __shared__ float rsr[512];
  __shared__ float red[256];
  const int r = blockIdx.x, tid = threadIdx.x;
  const int b = r >> 7, p = r & 127;
  int n = po[b * 128 + p]; n = n < 0 ? 0 : (n > 1023 ? 1023 : n);
  const u16* row = x + ((size_t)(b * 1024 + n)) * 512;
  rsr[tid] = us2f(row[tid]); rsr[tid + 256] = us2f(row[tid + 256]);
  __syncthreads();
  float t = ldf(b1, tid, f32);
  for (int k = 0; k < 512; k++) t += rsr[k] * ldf(W1, (size_t)k * 256 + tid, f32);
  t = t >= 0.f ? t : 0.1f * t;
  red[tid] = t * ldf(W2, tid, f32);
  __syncthreads();
  for (int off = 128; off > 0; off >>= 1) {
    if (tid < off) red[tid] += red[tid + off];
    __syncthreads();
  }
  if (tid == 0) {
    const float v = red[0] + ldf(b2, 0, f32);
    if (f32) ((float*)out)[r] = v; else ((u16*)out)[r] = f2bf(v);
  }
}

extern "C" void kernel_launch(void* const* d_in, const int* in_sizes, int n_in,
                              void* d_out, int out_size, void* d_ws, size_t ws_size,
                              hipStream_t stream) {
  (void)in_sizes; (void)out_size;
  const int D = 512, HID = 1024, L = 6;
  const int M = 8192;

  const int sh = (n_in >= 33) ? 0 : 1;
#define IN(k) d_in[(k) - (((k) >= 4) ? sh : 0)]
  const void* nf   = IN(0);
  const int* ind   = (const int*)IN(1);
  const int* outd  = (const int*)IN(2);
  const int* amask = (const int*)IN(4);
  const int* po    = (const int*)IN(5);
  const void* abias = IN(6);
  const void* ein  = IN(7);
  const void* eout = IN(8);
  const void* mnW1 = IN(9);  const void* mnb1 = IN(10);
  const void* mnW2 = IN(11); const void* mnb2 = IN(12);
  const void* Wq = IN(13); const void* bq = IN(14);
  const void* Wk = IN(15); const void* bk = IN(16);
  const void* Wv = IN(17); const void* bv = IN(18);
  const void* Wo = IN(19); const void* bo = IN(20);
  const void* ln1g = IN(21); const void* ln1b = IN(22);
  const void* W1 = IN(23); const void* b1 = IN(24);
  const void* W2 = IN(25); const void* b2 = IN(26);
  const void* ln2g = IN(27); const void* ln2b = IN(28);
  const void* oW1 = IN(29); const void* ob1 = IN(30);
  const void* oW2 = IN(31); const void* ob2 = IN(32);
#undef IN
  const void* probe = ln1g;

  // ws layout: x bf16 @0 (8M) | yb bf16 @8M (8M) | qkv bf16 [M][1536]
  // @16M (24M) | wt bf16 @40M (~4.2M: per-layer transposed weights+biases)
  // | biasm bf16 @45M (64M, if ws_size >= 109M; known >=112M from R1).
  // h1b = yb; hidb aliases qkv region (16M <= 24M).
  char* wsb = (char*)d_ws;
  u16* x   = (u16*)wsb;
  u16* yb  = (u16*)(wsb + ((size_t)8 << 20));
  u16* qkv = (u16*)(wsb + ((size_t)16 << 20));
  u16* wt  = (u16*)(wsb + ((size_t)40 << 20));
  u16* h1b = yb;
  u16* hidb = qkv;
  u16* biasm = (ws_size >= ((size_t)109 << 20))
                   ? (u16*)(wsb + ((size_t)45 << 20)) : (u16*)0;

  dim3 blk(256);
  if (biasm) bias_pack<<<8192, blk, 0, stream>>>(probe, abias, amask, biasm);
  // node MLP: convert weights once, then MFMA GEMMs (overwritten at layer 0)
  wconv_node<<<37, blk, 0, stream>>>(probe, mnW1, mnW2, mnb1, mnb2, wt);
  gemm_bt<64, 64><<<dim3(4, M / 128), blk, 0, stream>>>(probe, nf, 2, 64, wt, wt + 147456, nullptr, h1b, 1, M, 256, 64, 2);
  gemm_bt<64, 64><<<dim3(8, M / 128), blk, 0, stream>>>(probe, h1b, 1, 256, wt + 16384, wt + 147456 + 256, nullptr, x, 1, M, D, 256, 0);
  deg_kernel<<<M, blk, 0, stream>>>(probe, x, ind, outd, ein, eout);

  for (int l = 0; l < L; l++) {
    const size_t wO = (size_t)l * D * D, bO = (size_t)l * D;
    const size_t w1O = (size_t)l * D * HID, b1O = (size_t)l * HID;
    wconv_layer<<<513, blk, 0, stream>>>(probe, Wq, Wk, Wv, Wo, W1, W2,
                                         bq, bk, bv, bo, b1, b2, wO, w1O, bO, b1O, wt);
    gemm_bt<128, 32><<<dim3(12, M / 128), blk, 0, stream>>>(probe, x, 1, 512, wt, wt + 2097152, nullptr, qkv, 1, M, 1536, 512, 0);
    attn_mfma<<<dim3(16, 4, 8), blk, 0, stream>>>(probe, qkv, abias, amask, qkv, biasm);
    gemm_bt<64, 64><<<dim3(8, M / 128), blk, 0, stream>>>(probe, qkv, 1, 1536, wt + 786432, wt + 2097152 + 1536, x, yb, 1, M, D, D, 0);
    ln_kernel<<<M / 4, blk, 0, stream>>>(probe, yb, ln1g, ln1b, bO, x);
    gemm_bt<128, 32><<<dim3(8, M / 128), blk, 0, stream>>>(probe, x, 1, 512, wt + 1048576, wt + 2097152 + 2048, nullptr, hidb, 1, M, HID, 512, 1);
    gemm_bt<64, 64><<<dim3(8, M / 128), blk, 0, stream>>>(probe, hidb, 1, 1024, wt + 1572864, wt + 2097152 + 3072, x, yb, 1, M, D, HID, 0);
    ln_kernel<<<M / 4, blk, 0, stream>>>(probe, yb, ln2g, ln2b, bO, x);
  }
  final_kernel<<<1024, blk, 0, stream>>>(probe, x, po, oW1, ob1, oW2, ob2, d_out);
}